// Round 11
// baseline (705.666 us; speedup 1.0000x reference)
//
#include <hip/hip_runtime.h>

// R11: dual-tile (MB=32) staggered rotation, funded by R10's WH1-LDS eviction.
// R10 (643us, no spill, VGPR 120) proved WH1-in-LDS frees ~64 regs but its
// per-kt acc interleave put acc1's last MFMA at stream end -> ACT1 stalled with
// nothing to drain under it (no overlap, = R7). Fix the window: issue ALL acc1
// MFMAs first, then acc0A, then ACT1A-compute (overlaps acc0 drain), then
// acc0B, ACT1B-compute. Two independent 16-row tiles (MB=32, 256 blocks, ONE
// round) double per-wave work at only +1 acc set (max 3 live = 48 regs;
// weights 136). swh1 B-frags shared across tiles (LDS reads don't double).
// sh1 single-buffered (+B_mid) and x register-prefetched (R9 koff trick,
// correctness-proven) so LDS fits: 161.8KB. Canary: WRITE_SIZE >5MB = spill.

typedef _Float16 half_t;
typedef _Float16 half8 __attribute__((ext_vector_type(8)));
typedef _Float16 half4 __attribute__((ext_vector_type(4)));
typedef float f32x4 __attribute__((ext_vector_type(4)));

#define SEQ 100
#define FUT 30
#define TOT (SEQ + FUT)
#define NIN 15
#define MB  32
#define L2E 1.44269504f

#define MFMA32(A, B, C) __builtin_amdgcn_mfma_f32_16x16x32_f16((A), (B), (C), 0, 0, 0)
#define MFMA16(A, B, C) __builtin_amdgcn_mfma_f32_16x16x16f16((A), (B), (C), 0, 0, 0)

// ---- prep (identical to R10): fp16 repack, gate scales folded
// (i,f,o: -log2e ; cell g: +2log2e). n' = 64*wave + 16*gate + unit%16.
// ws halfword layout:
//   [0,      65536)  WH0 [n*128+k]
//   [65536, 131072)  WI1 [n*128+k]
//   [131072,196608)  WH1L[(c*512+n)*8+e]  c=k>>3, e=k&7  (LDS-ready order)
//   [196608,204800)  WX  [n*16+k]   (k>=15 zero)
//   [204800,206848)  BV: 1024 f32 = scaled (b_ih+b_hh), layer0 then layer1
__global__ void prep_kernel(const float* __restrict__ w_ih0, const float* __restrict__ w_hh0,
                            const float* __restrict__ b_ih0, const float* __restrict__ b_hh0,
                            const float* __restrict__ w_ih1, const float* __restrict__ w_hh1,
                            const float* __restrict__ b_ih1, const float* __restrict__ b_hh1,
                            half_t* __restrict__ wsh)
{
  int idx = blockIdx.x * 256 + threadIdx.x;
  if (idx < 131072) {
    int seg = idx >> 16;
    int r   = idx & 65535;
    int n   = r >> 7, k = r & 127;
    int g   = (n >> 4) & 3;
    int row = g * 128 + ((n >> 6) << 4) + (n & 15);
    float sc = (g == 2) ? (2.0f * L2E) : (-L2E);
    const float* src = (seg == 0) ? w_hh0 : w_ih1;
    wsh[idx] = (half_t)(src[row * 128 + k] * sc);
  } else if (idx < 196608) {
    int r   = idx - 131072;
    int c   = r >> 12;
    int rem = r & 4095;
    int n   = rem >> 3, e = rem & 7;
    int k   = c * 8 + e;
    int g   = (n >> 4) & 3;
    int row = g * 128 + ((n >> 6) << 4) + (n & 15);
    float sc = (g == 2) ? (2.0f * L2E) : (-L2E);
    wsh[idx] = (half_t)(w_hh1[row * 128 + k] * sc);
  } else if (idx < 204800) {
    int r   = idx - 196608;
    int n   = r >> 4, k = r & 15;
    int g   = (n >> 4) & 3;
    int row = g * 128 + ((n >> 6) << 4) + (n & 15);
    float sc = (g == 2) ? (2.0f * L2E) : (-L2E);
    wsh[idx] = (half_t)((k < NIN) ? (w_ih0[row * NIN + k] * sc) : 0.0f);
  } else if (idx < 205824) {
    int r     = idx - 204800;
    float* bv = (float*)(wsh + 204800);
    int which = r >> 9, n = r & 511;
    int g     = (n >> 4) & 3;
    int row   = g * 128 + ((n >> 6) << 4) + (n & 15);
    float sc  = (g == 2) ? (2.0f * L2E) : (-L2E);
    bv[r] = ((which == 0) ? (b_ih0[row] + b_hh0[row]) : (b_ih1[row] + b_hh1[row])) * sc;
  }
}

// lane's K16 x A-frag from a (possibly offset-11) float4 (R9-proven)
__device__ __forceinline__ half4 xfrag(float4 v, int quad) {
  float a = (quad < 3) ? v.x : v.y;
  float b = (quad < 3) ? v.y : v.z;
  float c = (quad < 3) ? v.z : v.w;
  float d = (quad < 3) ? v.w : 0.0f;
  return (half4){(half_t)a, (half_t)b, (half_t)c, (half_t)d};
}

__global__ __launch_bounds__(512, 2)
void lstm_kernel(const float* __restrict__ x,
                 const half_t* __restrict__ wsh,
                 const float* __restrict__ fcw,
                 const float* __restrict__ fcb,
                 float* __restrict__ out)
{
  // h tiles (R7 swizzle): (row m, col k) -> m*128 + (((k>>3) ^ (m&7))<<3) + (k&7)
  __shared__ __align__(16) half_t swh1[65536];        // 131,072 B  WH1 [c][n][8]
  __shared__ __align__(16) half_t sh0[2][MB * 128];   // 16,384 B (dbuf)
  __shared__ __align__(16) half_t sh1[MB * 128];      // 8,192 B  (single)
  __shared__ __align__(16) half_t sdec[4 * MB * 4];   // 1,024 B  [quad][b][4]
  __shared__ __align__(16) float  sbias[1024];        // 4,096 B
  __shared__ __align__(16) float  sfc[258];           // 1,032 B  => 161,800 B

  const half_t* WH0  = wsh;
  const half_t* WI1  = wsh + 65536;
  const half_t* WH1L = wsh + 131072;
  const half_t* WX   = wsh + 196608;
  const float*  BV   = (const float*)(wsh + 204800);

  const int tid   = threadIdx.x;
  const int wave  = tid >> 6;
  const int lane  = tid & 63;
  const int l16   = lane & 15;
  const int quad  = lane >> 4;
  const int nb    = wave * 64;
  const int bbase = blockIdx.x * MB;

  // ---- register weights: WH0 + WI1 (128) + WX (8) ----
  half8 wh0[4][4], wi1[4][4];  // [kt][g]
  #pragma unroll
  for (int kt = 0; kt < 4; ++kt) {
    #pragma unroll
    for (int g = 0; g < 4; ++g) {
      int n = nb + g * 16 + l16;
      int k = kt * 32 + quad * 8;
      wh0[kt][g] = *(const half8*)&WH0[n * 128 + k];
      wi1[kt][g] = *(const half8*)&WI1[n * 128 + k];
    }
  }
  half4 wxr[4];
  #pragma unroll
  for (int g = 0; g < 4; ++g)
    wxr[g] = *(const half4*)&WX[(nb + g * 16 + l16) * 16 + quad * 4];

  // ---- one-time LDS staging ----
  for (int it = tid; it < 8192; it += 512)
    ((uint4*)swh1)[it] = ((const uint4*)WH1L)[it];
  for (int it = tid; it < 1024; it += 512) sbias[it] = BV[it];
  if (tid < 256) sfc[tid] = fcw[tid];
  if (tid < 2)   sfc[256 + tid] = fcb[tid];
  {
    int b = tid >> 4, i = tid & 15;   // exactly 512 threads = 32 rows x 16
    float v = (i < NIN) ? x[(size_t)(bbase + b) * (SEQ * NIN) + 99 * NIN + i] : 0.f;
    sdec[(i >> 2) * (MB * 4) + b * 4 + (i & 3)] = (half_t)v;
  }
  for (int it = tid; it < MB * 128; it += 512) sh1[it] = (half_t)0;  // h1(-1)=0

  float c0A[4] = {0,0,0,0}, c0B[4] = {0,0,0,0};
  float c1A[4] = {0,0,0,0}, c1B[4] = {0,0,0,0};
  const int kc = wave * 2 + (l16 >> 3);

  // fused activation compute (R7-exact numerics):
  // c' = [c*(1+A)(1+B) + (B-1)(1+C)] / [(1+A)(1+B)(1+C)]
  // h  = (E-1) / [(1+D)(1+E)],  E = 2^(2*log2e*c')
  #define ACT_COMPUTE(ACC, CS, HV)                                             \
    _Pragma("unroll")                                                          \
    for (int r = 0; r < 4; ++r) {                                              \
      float A  = __builtin_amdgcn_exp2f((ACC)[0][r]);                          \
      float C  = __builtin_amdgcn_exp2f((ACC)[1][r]);                          \
      float B  = __builtin_amdgcn_exp2f((ACC)[2][r]);                          \
      float D  = __builtin_amdgcn_exp2f((ACC)[3][r]);                          \
      float oA = 1.f + A, oB = 1.f + B, oC = 1.f + C, oD = 1.f + D;            \
      float P  = oA * oB;                                                      \
      float t  = (B - 1.f) * oC;                                               \
      float nm = fmaf((CS)[r], P, t);                                          \
      float rc = __builtin_amdgcn_rcpf(P * oC);                                \
      float cn = nm * rc;                                                      \
      (CS)[r] = cn;                                                            \
      float E  = __builtin_amdgcn_exp2f(2.0f * L2E * cn);                      \
      float h  = (E - 1.f) * __builtin_amdgcn_rcpf(oD * (1.f + E));            \
      (HV)[r] = (half_t)h;                                                     \
    }

  #define STORE_H(HV, DST, ROWOFF)                                             \
    _Pragma("unroll")                                                          \
    for (int r = 0; r < 4; ++r) {                                              \
      int m = quad * 4 + r;                                                    \
      (DST)[(ROWOFF + m) * 128 + ((kc ^ (m & 7)) << 3) + (l16 & 7)] = (HV)[r]; \
    }

  // ---- x pointers (A-frag: row, k = quad*4; quad3 reads at 11) ----
  const int koff = (quad < 3) ? quad * 4 : 11;
  const float* xpA = x + (size_t)(bbase + l16) * (SEQ * NIN) + koff;
  const float* xpB = xpA + (size_t)16 * (SEQ * NIN);

  // ---- preamble: h0(0) = act(b0 + x(0)·wx) for both tiles -> sh0[0] ----
  {
    float4 x0A = *(const float4*)xpA;
    float4 x0B = *(const float4*)xpB;
    half4 axA = xfrag(x0A, quad), axB = xfrag(x0B, quad);
    f32x4 accA[4], accB[4];
    #pragma unroll
    for (int g = 0; g < 4; ++g) {
      float b = sbias[nb + g * 16 + l16];
      accA[g] = (f32x4){b, b, b, b};
      accB[g] = (f32x4){b, b, b, b};
    }
    #pragma unroll
    for (int g = 0; g < 4; ++g) {
      accA[g] = MFMA16(axA, wxr[g], accA[g]);
      accB[g] = MFMA16(axB, wxr[g], accB[g]);
    }
    half4 hA, hB;
    ACT_COMPUTE(accA, c0A, hA)
    ACT_COMPUTE(accB, c0B, hB)
    STORE_H(hA, sh0[0], 0)
    STORE_H(hB, sh0[0], 16)
  }
  xpA += NIN; xpB += NIN;
  float4 xfA = *(const float4*)xpA;   // x(1)
  float4 xfB = *(const float4*)xpB;
  __syncthreads();

  for (int s = 0; s < TOT - 1; ++s) {
    const int cur = s & 1, nxt = cur ^ 1;

    half4 axA, axB;
    if (s < SEQ) {
      if (s + 1 < SEQ) { axA = xfrag(xfA, quad); axB = xfrag(xfB, quad); }
      else {   // s=99: first decoder input = x(99) (sdec pre-update)
        axA = *(const half4*)&sdec[quad * (MB * 4) + l16 * 4];
        axB = *(const half4*)&sdec[quad * (MB * 4) + (16 + l16) * 4];
      }
    }
    if (s + 2 < SEQ) {   // prefetch x(s+2)
      xpA += NIN; xpB += NIN;
      xfA = *(const float4*)xpA;
      xfB = *(const float4*)xpB;
    }

    // ======== MFMA phase: acc1 (both tiles) FIRST ========
    f32x4 acc1A[4], acc1B[4];
    #pragma unroll
    for (int g = 0; g < 4; ++g) {
      float b = sbias[512 + nb + g * 16 + l16];
      acc1A[g] = (f32x4){b, b, b, b};
      acc1B[g] = (f32x4){b, b, b, b};
    }
    #pragma unroll
    for (int kt = 0; kt < 4; ++kt) {      // h1(s-1) x WH1 (LDS B, shared)
      int c  = kt * 4 + quad;
      int sw = ((c ^ (l16 & 7)) << 3);
      half8 a1A = *(const half8*)&sh1[l16 * 128 + sw];
      half8 a1B = *(const half8*)&sh1[(16 + l16) * 128 + sw];
      #pragma unroll
      for (int g = 0; g < 4; ++g) {
        half8 bw = *(const half8*)&swh1[(c * 512 + nb + g * 16 + l16) * 8];
        acc1A[g] = MFMA32(a1A, bw, acc1A[g]);
        acc1B[g] = MFMA32(a1B, bw, acc1B[g]);
      }
    }
    #pragma unroll
    for (int kt = 0; kt < 4; ++kt) {      // h0(s) x WI1 (reg B)
      int c  = kt * 4 + quad;
      int sw = ((c ^ (l16 & 7)) << 3);
      half8 a0A = *(const half8*)&sh0[cur][l16 * 128 + sw];
      half8 a0B = *(const half8*)&sh0[cur][(16 + l16) * 128 + sw];
      #pragma unroll
      for (int g = 0; g < 4; ++g) {
        acc1A[g] = MFMA32(a0A, wi1[kt][g], acc1A[g]);
        acc1B[g] = MFMA32(a0B, wi1[kt][g], acc1B[g]);
      }
    }

    // ---- acc0A, then ACT1A (overlaps acc0 drain), then acc0B, ACT1B ----
    f32x4 acc0A[4];
    #pragma unroll
    for (int g = 0; g < 4; ++g) {
      float b = sbias[nb + g * 16 + l16];
      acc0A[g] = (f32x4){b, b, b, b};
    }
    #pragma unroll
    for (int kt = 0; kt < 4; ++kt) {
      int c  = kt * 4 + quad;
      int sw = ((c ^ (l16 & 7)) << 3);
      half8 a0A = *(const half8*)&sh0[cur][l16 * 128 + sw];
      #pragma unroll
      for (int g = 0; g < 4; ++g) acc0A[g] = MFMA32(a0A, wh0[kt][g], acc0A[g]);
    }
    if (s < SEQ) {
      #pragma unroll
      for (int g = 0; g < 4; ++g) acc0A[g] = MFMA16(axA, wxr[g], acc0A[g]);
    }
    half4 h1Av;
    ACT_COMPUTE(acc1A, c1A, h1Av)

    f32x4 acc0B[4];
    #pragma unroll
    for (int g = 0; g < 4; ++g) {
      float b = sbias[nb + g * 16 + l16];
      acc0B[g] = (f32x4){b, b, b, b};
    }
    #pragma unroll
    for (int kt = 0; kt < 4; ++kt) {
      int c  = kt * 4 + quad;
      int sw = ((c ^ (l16 & 7)) << 3);
      half8 a0B = *(const half8*)&sh0[cur][(16 + l16) * 128 + sw];
      #pragma unroll
      for (int g = 0; g < 4; ++g) acc0B[g] = MFMA32(a0B, wh0[kt][g], acc0B[g]);
    }
    if (s < SEQ) {
      #pragma unroll
      for (int g = 0; g < 4; ++g) acc0B[g] = MFMA16(axB, wxr[g], acc0B[g]);
    }
    half4 h1Bv;
    ACT_COMPUTE(acc1B, c1B, h1Bv)

    __syncthreads();          // B_mid: all sh1/sh0 reads complete
    STORE_H(h1Av, sh1, 0)     // h1(s) into single-buffered sh1
    STORE_H(h1Bv, sh1, 16)

    if (s >= SEQ) {
      __syncthreads();        // B2d: h1(s) visible
      {                       // FC: all 512 threads (32 rows x 2 outs x 8 segs)
        int b   = wave * 4 + (lane >> 4);
        int o   = (lane >> 3) & 1;
        int seg = lane & 7;
        float p = 0.f;
        #pragma unroll
        for (int cc = 0; cc < 2; ++cc) {
          int c = seg * 2 + cc;
          half8 hv = *(const half8*)&sh1[b * 128 + ((c ^ (b & 7)) << 3)];
          f32x4 w0 = *(const f32x4*)&sfc[o * 128 + c * 8];
          f32x4 w1 = *(const f32x4*)&sfc[o * 128 + c * 8 + 4];
          #pragma unroll
          for (int u = 0; u < 4; ++u) p = fmaf((float)hv[u], w0[u], p);
          #pragma unroll
          for (int u = 0; u < 4; ++u) p = fmaf((float)hv[4 + u], w1[u], p);
        }
        p += __shfl_down(p, 4);
        p += __shfl_down(p, 2);
        p += __shfl_down(p, 1);
        if (seg == 0) {
          p += sfc[256 + o];
          out[(size_t)(bbase + b) * (FUT * 2) + (s - SEQ) * 2 + o] = p;
          sdec[b * 4 + o] = (half_t)p;   // [quad0][b][o] = features 0:2
        }
      }
      __syncthreads();        // B3d: sdec visible
      half4 dxA = *(const half4*)&sdec[quad * (MB * 4) + l16 * 4];
      half4 dxB = *(const half4*)&sdec[quad * (MB * 4) + (16 + l16) * 4];
      #pragma unroll
      for (int g = 0; g < 4; ++g) {
        acc0A[g] = MFMA16(dxA, wxr[g], acc0A[g]);
        acc0B[g] = MFMA16(dxB, wxr[g], acc0B[g]);
      }
    }

    // ---- ACT0 -> sh0[nxt] ----
    {
      half4 h0Av, h0Bv;
      ACT_COMPUTE(acc0A, c0A, h0Av)
      STORE_H(h0Av, sh0[nxt], 0)
      ACT_COMPUTE(acc0B, c0B, h0Bv)
      STORE_H(h0Bv, sh0[nxt], 16)
    }
    __syncthreads();          // B_end: h1(s), h0(s+1) visible
  }

  // ---- epilogue: gates1(129) both tiles + final FC ----
  {
    const int cur = (TOT - 1) & 1;   // 129 & 1 = 1
    f32x4 acc1A[4], acc1B[4];
    #pragma unroll
    for (int g = 0; g < 4; ++g) {
      float b = sbias[512 + nb + g * 16 + l16];
      acc1A[g] = (f32x4){b, b, b, b};
      acc1B[g] = (f32x4){b, b, b, b};
    }
    #pragma unroll
    for (int kt = 0; kt < 4; ++kt) {
      int c  = kt * 4 + quad;
      int sw = ((c ^ (l16 & 7)) << 3);
      half8 a1A = *(const half8*)&sh1[l16 * 128 + sw];
      half8 a1B = *(const half8*)&sh1[(16 + l16) * 128 + sw];
      #pragma unroll
      for (int g = 0; g < 4; ++g) {
        half8 bw = *(const half8*)&swh1[(c * 512 + nb + g * 16 + l16) * 8];
        acc1A[g] = MFMA32(a1A, bw, acc1A[g]);
        acc1B[g] = MFMA32(a1B, bw, acc1B[g]);
      }
    }
    #pragma unroll
    for (int kt = 0; kt < 4; ++kt) {
      int c  = kt * 4 + quad;
      int sw = ((c ^ (l16 & 7)) << 3);
      half8 a0A = *(const half8*)&sh0[cur][l16 * 128 + sw];
      half8 a0B = *(const half8*)&sh0[cur][(16 + l16) * 128 + sw];
      #pragma unroll
      for (int g = 0; g < 4; ++g) {
        acc1A[g] = MFMA32(a0A, wi1[kt][g], acc1A[g]);
        acc1B[g] = MFMA32(a0B, wi1[kt][g], acc1B[g]);
      }
    }
    half4 h1Av, h1Bv;
    ACT_COMPUTE(acc1A, c1A, h1Av)
    ACT_COMPUTE(acc1B, c1B, h1Bv)
    __syncthreads();
    STORE_H(h1Av, sh1, 0)
    STORE_H(h1Bv, sh1, 16)
    __syncthreads();
    {
      int b   = wave * 4 + (lane >> 4);
      int o   = (lane >> 3) & 1;
      int seg = lane & 7;
      float p = 0.f;
      #pragma unroll
      for (int cc = 0; cc < 2; ++cc) {
        int c = seg * 2 + cc;
        half8 hv = *(const half8*)&sh1[b * 128 + ((c ^ (b & 7)) << 3)];
        f32x4 w0 = *(const f32x4*)&sfc[o * 128 + c * 8];
        f32x4 w1 = *(const f32x4*)&sfc[o * 128 + c * 8 + 4];
        #pragma unroll
        for (int u = 0; u < 4; ++u) p = fmaf((float)hv[u], w0[u], p);
        #pragma unroll
        for (int u = 0; u < 4; ++u) p = fmaf((float)hv[4 + u], w1[u], p);
      }
      p += __shfl_down(p, 4);
      p += __shfl_down(p, 2);
      p += __shfl_down(p, 1);
      if (seg == 0) {
        p += sfc[256 + o];
        out[(size_t)(bbase + b) * (FUT * 2) + (FUT - 1) * 2 + o] = p;
      }
    }
  }
}

extern "C" void kernel_launch(void* const* d_in, const int* in_sizes, int n_in,
                              void* d_out, int out_size, void* d_ws, size_t ws_size,
                              hipStream_t stream)
{
  (void)in_sizes; (void)n_in; (void)out_size; (void)ws_size;
  const float* x     = (const float*)d_in[0];
  const float* w_ih0 = (const float*)d_in[1];
  const float* w_hh0 = (const float*)d_in[2];
  const float* b_ih0 = (const float*)d_in[3];
  const float* b_hh0 = (const float*)d_in[4];
  const float* w_ih1 = (const float*)d_in[5];
  const float* w_hh1 = (const float*)d_in[6];
  const float* b_ih1 = (const float*)d_in[7];
  const float* b_hh1 = (const float*)d_in[8];
  const float* fcw   = (const float*)d_in[9];
  const float* fcb   = (const float*)d_in[10];
  float*  out = (float*)d_out;
  half_t* wsh = (half_t*)d_ws;

  prep_kernel<<<(205824 + 255) / 256, 256, 0, stream>>>(
      w_ih0, w_hh0, b_ih0, b_hh0, w_ih1, w_hh1, b_ih1, b_hh1, wsh);
  lstm_kernel<<<8192 / MB, 512, 0, stream>>>(x, wsh, fcw, fcb, out);
}